// Round 6
// baseline (12114.467 us; speedup 1.0000x reference)
//
#include <hip/hip_runtime.h>

#define TT 4096

typedef __attribute__((ext_vector_type(2))) unsigned int u2v;
typedef __attribute__((ext_vector_type(4))) unsigned int u4v;
typedef __attribute__((ext_vector_type(2))) __fp16 f16x2;
typedef __attribute__((ext_vector_type(2))) _Float16 F16x2;
union HU { unsigned int u; f16x2 hf; F16x2 hF; };

// ws layout (float offsets):
//   M    @ 0      : 2048*64 = 131072   (W_in @ C)
//   wtil @ 131072 : 64                 (C^T @ dense_W[:64])
//   yp   @ 131200 : 4096*64 = 262144   (per-WG dense partials, plain stores)
//   hpub @ 393344 : 2 slots * 1024 packets * (u32 data, u32 tag) = 4096 u32
// hpub needs NO init: harness poisons ws to 0xAA -> tag never matches t+1;
// within a run every parity slot is fully rewritten every 2 steps, so no
// stale tag can alias a future tg.

__global__ void esn_prep(const float* __restrict__ C,
                         const float* __restrict__ Win,
                         const float* __restrict__ dW,
                         float* __restrict__ M,
                         float* __restrict__ wtil) {
  __shared__ float s[64];
  const int b = blockIdx.x, i = threadIdx.x;
  if (b < 2048) {
    s[i] = Win[b * 64 + i];
    __syncthreads();
    float acc = 0.f;
#pragma unroll 16
    for (int d = 0; d < 64; ++d) acc += s[d] * C[d * 64 + i];
    M[b * 64 + i] = acc;
  } else {
    s[i] = dW[i];
    __syncthreads();
    float acc = 0.f;
    for (int d = 0; d < 64; ++d) acc += s[d] * C[d * 64 + i];
    wtil[i] = acc;
  }
}

// Call-free tanh: tanh(x) = 1 - 2/(exp(2x)+1)
__device__ __forceinline__ float fast_tanh(float x) {
  const float e = __builtin_amdgcn_exp2f(x * 2.8853900817779268f);  // exp(2x)
  return 1.0f - 2.0f * __builtin_amdgcn_rcpf(e + 1.0f);
}

// fp16-pair dot with fp32 accumulate: v_dot2_f32_f16 where available.
__device__ __forceinline__ float fdot2f(const HU a, const HU b, float c) {
#if __has_builtin(__builtin_amdgcn_fdot2)
  return __builtin_amdgcn_fdot2(a.hF, b.hF, c, false);
#else
  return c + (float)a.hf.x * (float)b.hf.x + (float)a.hf.y * (float)b.hf.y;
#endif
}

// lgkm-only barrier: __syncthreads() drains vmcnt(0) too, which puts the
// X-prefetch / publish-ack on the critical path. Neither step barrier hands
// off global data (h goes via tag-validated board; yp consumed post-kernel),
// so LDS-visibility (lgkmcnt) + s_barrier is sufficient.
#define BARK() asm volatile("s_waitcnt lgkmcnt(0)\n\ts_barrier" ::: "memory")

// Issue 16 batched board loads (lane L owns packets {64p+L}).
#define PISSUE(P, WAITSTR)                                              \
  asm volatile(                                                         \
      "global_load_dwordx2 %0, %16, off sc0 sc1\n\t"                    \
      "global_load_dwordx2 %1, %16, off offset:512 sc0 sc1\n\t"         \
      "global_load_dwordx2 %2, %16, off offset:1024 sc0 sc1\n\t"        \
      "global_load_dwordx2 %3, %16, off offset:1536 sc0 sc1\n\t"        \
      "global_load_dwordx2 %4, %16, off offset:2048 sc0 sc1\n\t"        \
      "global_load_dwordx2 %5, %16, off offset:2560 sc0 sc1\n\t"        \
      "global_load_dwordx2 %6, %16, off offset:3072 sc0 sc1\n\t"        \
      "global_load_dwordx2 %7, %16, off offset:3584 sc0 sc1\n\t"        \
      "global_load_dwordx2 %8, %17, off sc0 sc1\n\t"                    \
      "global_load_dwordx2 %9, %17, off offset:512 sc0 sc1\n\t"         \
      "global_load_dwordx2 %10, %17, off offset:1024 sc0 sc1\n\t"       \
      "global_load_dwordx2 %11, %17, off offset:1536 sc0 sc1\n\t"       \
      "global_load_dwordx2 %12, %17, off offset:2048 sc0 sc1\n\t"       \
      "global_load_dwordx2 %13, %17, off offset:2560 sc0 sc1\n\t"       \
      "global_load_dwordx2 %14, %17, off offset:3072 sc0 sc1\n\t"       \
      "global_load_dwordx2 %15, %17, off offset:3584 sc0 sc1" WAITSTR   \
      : "=&v"(P##0), "=&v"(P##1), "=&v"(P##2), "=&v"(P##3),             \
        "=&v"(P##4), "=&v"(P##5), "=&v"(P##6), "=&v"(P##7),             \
        "=&v"(P##8), "=&v"(P##9), "=&v"(P##a), "=&v"(P##b),             \
        "=&v"(P##c), "=&v"(P##d), "=&v"(P##e), "=&v"(P##f)              \
      : "v"(b0), "v"(b1)                                                \
      : "memory")

// Force re-read of a batch's regs after a preceding volatile wait block.
#define REGBAR(P)                                                       \
  asm volatile("" : "+v"(P##0), "+v"(P##1), "+v"(P##2), "+v"(P##3),     \
                    "+v"(P##4), "+v"(P##5), "+v"(P##6), "+v"(P##7),     \
                    "+v"(P##8), "+v"(P##9), "+v"(P##a), "+v"(P##b),     \
                    "+v"(P##c), "+v"(P##d), "+v"(P##e), "+v"(P##f))

// NOTE: (P##0).y not P##0.y -- "0.y" lexes as one pp-number token and the
// paste would form the invalid token "A0.y" (round-5 compile failure).
#define CHK(P)                                                          \
  __all(((P##0).y == tg) && ((P##1).y == tg) && ((P##2).y == tg) &&     \
        ((P##3).y == tg) && ((P##4).y == tg) && ((P##5).y == tg) &&     \
        ((P##6).y == tg) && ((P##7).y == tg) && ((P##8).y == tg) &&     \
        ((P##9).y == tg) && ((P##a).y == tg) && ((P##b).y == tg) &&     \
        ((P##c).y == tg) && ((P##d).y == tg) && ((P##e).y == tg) &&     \
        ((P##f).y == tg))

#define REPACK(P)                                                       \
  do {                                                                  \
    shh[lane] = (P##0).x;          shh[64 + lane] = (P##1).x;           \
    shh[128 + lane] = (P##2).x;    shh[192 + lane] = (P##3).x;          \
    shh[256 + lane] = (P##4).x;    shh[320 + lane] = (P##5).x;          \
    shh[384 + lane] = (P##6).x;    shh[448 + lane] = (P##7).x;          \
    shh[512 + lane] = (P##8).x;    shh[576 + lane] = (P##9).x;          \
    shh[640 + lane] = (P##a).x;    shh[704 + lane] = (P##b).x;          \
    shh[768 + lane] = (P##c).x;    shh[832 + lane] = (P##d).x;          \
    shh[896 + lane] = (P##e).x;    shh[960 + lane] = (P##f).x;          \
  } while (0)

// 64 WGs x 1024 threads; WG owns 32 rows (2/wave); W in VGPRs (r3, proven).
// v6 exchange = r3 board/wire-format with three serial-path cuts:
//  * IMMEDIATE ATOMIC PUBLISH: lane0 of each wave fires a device-scope
//    atomicExch of its tagged 8-B packet the moment its rows reduce --
//    before barrier-1, no LDS gather. Atomics execute at the coherence
//    point, skipping lazy L2-writeback visibility (suspect for r3's ~4.5
//    board-reads/step of FETCH). Tag-embedded packets keep this safe.
//  * LGKM-ONLY BARRIERS: removes vmcnt(0) drains (X-prefetch, publish-ack)
//    from both per-step barriers.
//  * PIPELINED A/B POLL: two 16-load batches in flight, vmcnt(16) partial
//    waits (in-order drain: waiting on one batch == other batch complete).
//    Halves sampling quantization. Acceptance is value-gated (tag==tg), so
//    any stale register read costs a round, never wrong data.
//  Slot-reuse transitivity unchanged: publish-at-t+1 happens after compute
//  t+1, which follows BAR2 of t, which follows the WG's completed t-poll.
__global__ __launch_bounds__(1024) void esn_recur(
    const float* __restrict__ X, const float* __restrict__ M,
    const float* __restrict__ W, const float* __restrict__ dW,
    unsigned int* __restrict__ hpub, float* __restrict__ yp) {
  __shared__ unsigned int shh[1024];  // 2048 fp16 h as packed pairs
  __shared__ float psm[16];           // per-wave dense partials
  const int tid = threadIdx.x;
  const int lane = tid & 63;
  const int wave = tid >> 6;
  const int b = blockIdx.x;
  const int r0 = b * 32 + wave * 2;
  const float m0 = M[r0 * 64 + lane];
  const float m1 = M[(r0 + 1) * 64 + lane];
  const float dw0 = dW[64 + r0];
  const float dw1 = dW[64 + r0 + 1];
  // one-time: this lane's W fragment -> 32 persistent VGPRs (packed fp16).
  u4v wA[4], wB[4];
#pragma unroll
  for (int j = 0; j < 4; ++j) {
    const float* p0 = W + (size_t)r0 * 2048 + 512 * j + 8 * lane;
    const float* p1 = p0 + 2048;
    const float4 a = *(const float4*)p0;
    const float4 c = *(const float4*)(p0 + 4);
    const float4 d = *(const float4*)p1;
    const float4 e = *(const float4*)(p1 + 4);
    HU t0, t1, t2, t3;
    t0.hf = __builtin_amdgcn_cvt_pkrtz(a.x, a.y);
    t1.hf = __builtin_amdgcn_cvt_pkrtz(a.z, a.w);
    t2.hf = __builtin_amdgcn_cvt_pkrtz(c.x, c.y);
    t3.hf = __builtin_amdgcn_cvt_pkrtz(c.z, c.w);
    wA[j][0] = t0.u; wA[j][1] = t1.u; wA[j][2] = t2.u; wA[j][3] = t3.u;
    t0.hf = __builtin_amdgcn_cvt_pkrtz(d.x, d.y);
    t1.hf = __builtin_amdgcn_cvt_pkrtz(d.z, d.w);
    t2.hf = __builtin_amdgcn_cvt_pkrtz(e.x, e.y);
    t3.hf = __builtin_amdgcn_cvt_pkrtz(e.z, e.w);
    wB[j][0] = t0.u; wB[j][1] = t1.u; wB[j][2] = t2.u; wB[j][3] = t3.u;
  }
  shh[tid] = 0u;  // h_{-1} = 0
  __syncthreads();

  float xv = X[lane];

  for (int t = 0; t < TT; ++t) {
    // ---- compute 2 rows/wave: W from VGPR, h from LDS ----
    float a0 = m0 * xv, a1 = m1 * xv;
#pragma unroll
    for (int j = 0; j < 4; ++j) {
      const u4v hv = *(const u4v*)(shh + 4 * lane + 256 * j);
#pragma unroll
      for (int k = 0; k < 4; ++k) {
        HU ha, wa, wb;
        ha.u = hv[k]; wa.u = wA[j][k]; wb.u = wB[j][k];
        a0 = fdot2f(wa, ha, a0);
        a1 = fdot2f(wb, ha, a1);
      }
    }
#pragma unroll
    for (int off = 32; off; off >>= 1) {
      a0 += __shfl_xor(a0, off, 64);
      a1 += __shfl_xor(a1, off, 64);
    }
    const unsigned tg = (unsigned)t + 1u;
    unsigned int* slot = hpub + ((t & 1) << 11);
    const int tn = (t + 1 < TT) ? t + 1 : t;
    const float xnext = X[tn * 64 + lane];  // prefetch: hides under poll
    if (lane == 0) {
      const float h0 = fast_tanh(a0);
      const float h1 = fast_tanh(a1);
      HU pk; pk.hf = __builtin_amdgcn_cvt_pkrtz(h0, h1);
      psm[wave] = dw0 * h0 + dw1 * h1;
      if (t + 1 < TT) {
        // immediate publish: device-scope atomic at the coherence point,
        // fire-and-forget, no barrier/gather gating.
        const unsigned long long pk64 =
            ((unsigned long long)tg << 32) | (unsigned long long)pk.u;
        (void)__hip_atomic_exchange(
            (unsigned long long*)(slot + 2 * (16 * b + wave)), pk64,
            __ATOMIC_RELAXED, __HIP_MEMORY_SCOPE_AGENT);
      }
    }
    BARK();  // psm visible; all shh reads of step t done
    if (wave == 0) {
      if (t + 1 < TT) {
        const unsigned int* b0 = slot + 2 * lane;
        const unsigned int* b1 = b0 + 1024;
        u2v A0, A1, A2, A3, A4, A5, A6, A7, A8, A9, Aa, Ab, Ac, Ad, Ae, Af;
        u2v B0, B1, B2, B3, B4, B5, B6, B7, B8, B9, Ba, Bb, Bc, Bd, Be, Bf;
        // WAW guard for batch-reg reuse across steps; vmcnt(1) tolerates
        // this wave's own just-issued publish atomic (newest op).
        asm volatile("s_waitcnt vmcnt(1)" ::: "memory");
        PISSUE(A, "");                              // issue A
        PISSUE(B, "\n\ts_waitcnt vmcnt(16)");       // issue B; A(+atomic) done
        REGBAR(A);
        bool useB = false;
        bool got = CHK(A);
        if (!got) {
          for (;;) {
            PISSUE(A, "\n\ts_waitcnt vmcnt(16)");   // reissue A; B done
            REGBAR(B);
            if (CHK(B)) { useB = true; break; }
            PISSUE(B, "\n\ts_waitcnt vmcnt(16)");   // reissue B; A done
            REGBAR(A);
            if (CHK(A)) { useB = false; break; }
          }
        }
        if (useB) REPACK(B); else REPACK(A);
      }
    } else if (tid == 64) {
      // dense partial for step t (parallel with wave0's poll)
      float s = 0.f;
#pragma unroll
      for (int wv = 0; wv < 16; ++wv) s += psm[wv];
      yp[t * 64 + b] = s;
    }
    BARK();  // shh now holds h_t
    xv = xnext;
  }
}

__global__ void esn_out(const float* __restrict__ X,
                        const float* __restrict__ wtil,
                        const float* __restrict__ yp,
                        const float* __restrict__ bptr,
                        float* __restrict__ out) {
  const int tid = threadIdx.x;
  const int lane = tid & 63;
  const int wave = tid >> 6;
  const int t = blockIdx.x * 4 + wave;
  float v = wtil[lane] * X[t * 64 + lane] + yp[t * 64 + lane];
#pragma unroll
  for (int off = 32; off; off >>= 1) v += __shfl_xor(v, off, 64);
  if (lane == 0) out[t] = v + bptr[0];
}

extern "C" void kernel_launch(void* const* d_in, const int* in_sizes, int n_in,
                              void* d_out, int out_size, void* d_ws, size_t ws_size,
                              hipStream_t stream) {
  const float* X   = (const float*)d_in[0];
  const float* C   = (const float*)d_in[1];
  const float* Win = (const float*)d_in[2];
  const float* W   = (const float*)d_in[3];
  const float* dW  = (const float*)d_in[4];
  const float* db  = (const float*)d_in[5];
  float* ws   = (float*)d_ws;
  float* M    = ws;
  float* wtil = ws + 131072;
  float* yp   = ws + 131200;
  unsigned int* hpub = (unsigned int*)(ws + 393344);

  esn_prep<<<2049, 64, 0, stream>>>(C, Win, dW, M, wtil);

  void* args[] = {(void*)&X, (void*)&M, (void*)&W, (void*)&dW,
                  (void*)&hpub, (void*)&yp};
  (void)hipLaunchCooperativeKernel(reinterpret_cast<void*>(&esn_recur), dim3(64),
                                   dim3(1024), args, 0, stream);

  esn_out<<<1024, 256, 0, stream>>>(X, wtil, yp, db, (float*)d_out);
}

// Round 7
// 9736.198 us; speedup vs baseline: 1.2443x; 1.2443x over previous
//
#include <hip/hip_runtime.h>

#define TT 4096

typedef __attribute__((ext_vector_type(2))) unsigned int u2v;
typedef __attribute__((ext_vector_type(4))) unsigned int u4v;
typedef __attribute__((ext_vector_type(2))) __fp16 f16x2;
typedef __attribute__((ext_vector_type(2))) _Float16 F16x2;
union HU { unsigned int u; f16x2 hf; F16x2 hF; };

// ws layout (float offsets):
//   M    @ 0      : 2048*64 = 131072   (W_in @ C)
//   wtil @ 131072 : 64                 (C^T @ dense_W[:64])
//   yp   @ 131200 : 4096*64 = 262144   (per-WG dense partials, plain stores)
//   hpub @ 393344 : 2 slots * 1024 packets * (u32 data, u32 tag) = 4096 u32
// hpub needs NO init: harness poisons ws to 0xAA -> tag never matches t+1.
//
// LAW (r1/r2/r6 regressions, 3x confirmed): publish MUST be one coalesced
// wave-wide store burst from ONE wave after a gather barrier. Scattered or
// per-wave system-scope writes into shared lines serialize line ownership
// and delay packet arrival more than they save in gather latency.

__global__ void esn_prep(const float* __restrict__ C,
                         const float* __restrict__ Win,
                         const float* __restrict__ dW,
                         float* __restrict__ M,
                         float* __restrict__ wtil) {
  __shared__ float s[64];
  const int b = blockIdx.x, i = threadIdx.x;
  if (b < 2048) {
    s[i] = Win[b * 64 + i];
    __syncthreads();
    float acc = 0.f;
#pragma unroll 16
    for (int d = 0; d < 64; ++d) acc += s[d] * C[d * 64 + i];
    M[b * 64 + i] = acc;
  } else {
    s[i] = dW[i];
    __syncthreads();
    float acc = 0.f;
    for (int d = 0; d < 64; ++d) acc += s[d] * C[d * 64 + i];
    wtil[i] = acc;
  }
}

// Call-free tanh: tanh(x) = 1 - 2/(exp(2x)+1)
__device__ __forceinline__ float fast_tanh(float x) {
  const float e = __builtin_amdgcn_exp2f(x * 2.8853900817779268f);  // exp(2x)
  return 1.0f - 2.0f * __builtin_amdgcn_rcpf(e + 1.0f);
}

// fp16-pair dot with fp32 accumulate: v_dot2_f32_f16 where available.
__device__ __forceinline__ float fdot2f(const HU a, const HU b, float c) {
#if __has_builtin(__builtin_amdgcn_fdot2)
  return __builtin_amdgcn_fdot2(a.hF, b.hF, c, false);
#else
  return c + (float)a.hf.x * (float)b.hf.x + (float)a.hf.y * (float)b.hf.y;
#endif
}

// lgkm-only barrier: __syncthreads() emits s_waitcnt vmcnt(0) before
// s_barrier, draining the X prefetch / publish-ack on the critical path.
// Neither step barrier hands off global data (h goes through the
// tag-validated board; yp is consumed by a later kernel), so LDS
// visibility (lgkmcnt) + s_barrier is sufficient.
#define BARK() asm volatile("s_waitcnt lgkmcnt(0)\n\ts_barrier" ::: "memory")

// Issue 16 batched board loads (lane L owns packets {64p+L}).
#define PISSUE(P, WAITSTR)                                              \
  asm volatile(                                                         \
      "global_load_dwordx2 %0, %16, off sc0 sc1\n\t"                    \
      "global_load_dwordx2 %1, %16, off offset:512 sc0 sc1\n\t"         \
      "global_load_dwordx2 %2, %16, off offset:1024 sc0 sc1\n\t"        \
      "global_load_dwordx2 %3, %16, off offset:1536 sc0 sc1\n\t"        \
      "global_load_dwordx2 %4, %16, off offset:2048 sc0 sc1\n\t"        \
      "global_load_dwordx2 %5, %16, off offset:2560 sc0 sc1\n\t"        \
      "global_load_dwordx2 %6, %16, off offset:3072 sc0 sc1\n\t"        \
      "global_load_dwordx2 %7, %16, off offset:3584 sc0 sc1\n\t"        \
      "global_load_dwordx2 %8, %17, off sc0 sc1\n\t"                    \
      "global_load_dwordx2 %9, %17, off offset:512 sc0 sc1\n\t"         \
      "global_load_dwordx2 %10, %17, off offset:1024 sc0 sc1\n\t"       \
      "global_load_dwordx2 %11, %17, off offset:1536 sc0 sc1\n\t"       \
      "global_load_dwordx2 %12, %17, off offset:2048 sc0 sc1\n\t"       \
      "global_load_dwordx2 %13, %17, off offset:2560 sc0 sc1\n\t"       \
      "global_load_dwordx2 %14, %17, off offset:3072 sc0 sc1\n\t"       \
      "global_load_dwordx2 %15, %17, off offset:3584 sc0 sc1" WAITSTR   \
      : "=&v"(P##0), "=&v"(P##1), "=&v"(P##2), "=&v"(P##3),             \
        "=&v"(P##4), "=&v"(P##5), "=&v"(P##6), "=&v"(P##7),             \
        "=&v"(P##8), "=&v"(P##9), "=&v"(P##a), "=&v"(P##b),             \
        "=&v"(P##c), "=&v"(P##d), "=&v"(P##e), "=&v"(P##f)              \
      : "v"(b0), "v"(b1)                                                \
      : "memory")

// Force re-read of a batch's regs after a preceding volatile wait block
// (rule #18: plain-code reads of asm-written regs can hoist past waits).
#define REGBAR(P)                                                       \
  asm volatile("" : "+v"(P##0), "+v"(P##1), "+v"(P##2), "+v"(P##3),     \
                    "+v"(P##4), "+v"(P##5), "+v"(P##6), "+v"(P##7),     \
                    "+v"(P##8), "+v"(P##9), "+v"(P##a), "+v"(P##b),     \
                    "+v"(P##c), "+v"(P##d), "+v"(P##e), "+v"(P##f))

// (P##0).y not P##0.y: "0.y" lexes as one pp-number token (r5 failure).
#define CHK(P)                                                          \
  __all(((P##0).y == tg) && ((P##1).y == tg) && ((P##2).y == tg) &&     \
        ((P##3).y == tg) && ((P##4).y == tg) && ((P##5).y == tg) &&     \
        ((P##6).y == tg) && ((P##7).y == tg) && ((P##8).y == tg) &&     \
        ((P##9).y == tg) && ((P##a).y == tg) && ((P##b).y == tg) &&     \
        ((P##c).y == tg) && ((P##d).y == tg) && ((P##e).y == tg) &&     \
        ((P##f).y == tg))

#define REPACK(P)                                                       \
  do {                                                                  \
    shh[lane] = (P##0).x;          shh[64 + lane] = (P##1).x;           \
    shh[128 + lane] = (P##2).x;    shh[192 + lane] = (P##3).x;          \
    shh[256 + lane] = (P##4).x;    shh[320 + lane] = (P##5).x;          \
    shh[384 + lane] = (P##6).x;    shh[448 + lane] = (P##7).x;          \
    shh[512 + lane] = (P##8).x;    shh[576 + lane] = (P##9).x;          \
    shh[640 + lane] = (P##a).x;    shh[704 + lane] = (P##b).x;          \
    shh[768 + lane] = (P##c).x;    shh[832 + lane] = (P##d).x;          \
    shh[896 + lane] = (P##e).x;    shh[960 + lane] = (P##f).x;          \
  } while (0)

// 64 WGs x 1024 threads; WG owns 32 rows (2/wave); W in VGPRs (r3 proven);
// r3 publish protocol (coalesced wave0 burst after gather barrier) FROZEN.
// v7 = r3 + fully hand-counted vmem queue:
//  * BARK barriers (no vmcnt(0) drains at the two step barriers).
//  * X prefetch is an ASM load with counted waits. Compiler-emitted loads
//    consumed in-loop force conservative vmcnt(0) (compiler can't count asm
//    loads) -- that drained the poll pipeline. Hand accounting: wave0's
//    queue at each point is known exactly:
//      compute-start: [stale_poll x16, xnext(retired)] -> vmcnt(16), free
//      others:        [xnext]                          -> vmcnt(0), free
//      poll-start:    [stale x16, xnext, store] -> guard vmcnt(2)
//      after issue A,B: vmcnt(16) retires exactly xnext+store+A.
//  * A/B pipelined poll: two 16-load batches alternate; sampling period
//    halves. Acceptance is value-gated (tag==tg): stale regs cost a round,
//    never wrong data. Every poll exit leaves exactly one batch (16) in
//    flight -> the guard's count is invariant.
__global__ __launch_bounds__(1024) void esn_recur(
    const float* __restrict__ X, const float* __restrict__ M,
    const float* __restrict__ W, const float* __restrict__ dW,
    unsigned int* __restrict__ hpub, float* __restrict__ yp) {
  __shared__ unsigned int shh[1024];  // 2048 fp16 h as packed pairs
  __shared__ unsigned int pub[16];    // per-wave packed h pairs
  __shared__ float psm[16];           // per-wave dense partials
  const int tid = threadIdx.x;
  const int lane = tid & 63;
  const int wave = tid >> 6;
  const int b = blockIdx.x;
  const int r0 = b * 32 + wave * 2;
  const float m0 = M[r0 * 64 + lane];
  const float m1 = M[(r0 + 1) * 64 + lane];
  const float dw0 = dW[64 + r0];
  const float dw1 = dW[64 + r0 + 1];
  // one-time: this lane's W fragment -> 32 persistent VGPRs (packed fp16).
  u4v wA[4], wB[4];
#pragma unroll
  for (int j = 0; j < 4; ++j) {
    const float* p0 = W + (size_t)r0 * 2048 + 512 * j + 8 * lane;
    const float* p1 = p0 + 2048;
    const float4 a = *(const float4*)p0;
    const float4 c = *(const float4*)(p0 + 4);
    const float4 d = *(const float4*)p1;
    const float4 e = *(const float4*)(p1 + 4);
    HU t0, t1, t2, t3;
    t0.hf = __builtin_amdgcn_cvt_pkrtz(a.x, a.y);
    t1.hf = __builtin_amdgcn_cvt_pkrtz(a.z, a.w);
    t2.hf = __builtin_amdgcn_cvt_pkrtz(c.x, c.y);
    t3.hf = __builtin_amdgcn_cvt_pkrtz(c.z, c.w);
    wA[j][0] = t0.u; wA[j][1] = t1.u; wA[j][2] = t2.u; wA[j][3] = t3.u;
    t0.hf = __builtin_amdgcn_cvt_pkrtz(d.x, d.y);
    t1.hf = __builtin_amdgcn_cvt_pkrtz(d.z, d.w);
    t2.hf = __builtin_amdgcn_cvt_pkrtz(e.x, e.y);
    t3.hf = __builtin_amdgcn_cvt_pkrtz(e.z, e.w);
    wB[j][0] = t0.u; wB[j][1] = t1.u; wB[j][2] = t2.u; wB[j][3] = t3.u;
  }
  shh[tid] = 0u;  // h_{-1} = 0
  // IMPORTANT: all compiler-emitted prologue loads (M, dW, W) are BEFORE
  // this barrier, so the waitcnt pass drains them here, not inside the loop.
  __syncthreads();

  // prologue X row: issue + one-time full drain
  float xq;
  {
    const float* xp0 = X + lane;
    asm volatile("global_load_dword %0, %1, off" : "=&v"(xq) : "v"(xp0)
                 : "memory");
    asm volatile("s_waitcnt vmcnt(0)" : "+v"(xq) :: "memory");
  }

  for (int t = 0; t < TT; ++t) {
    // ---- xv ready-wait: counted, never drains the poll pipeline ----
    if (wave == 0) {
      asm volatile("s_waitcnt vmcnt(16)" : "+v"(xq) :: "memory");
    } else {
      asm volatile("s_waitcnt vmcnt(0)" : "+v"(xq) :: "memory");
    }
    const float xv = xq;
    // ---- compute 2 rows/wave: W from VGPR, h from LDS ----
    float a0 = m0 * xv, a1 = m1 * xv;
#pragma unroll
    for (int j = 0; j < 4; ++j) {
      const u4v hv = *(const u4v*)(shh + 4 * lane + 256 * j);
#pragma unroll
      for (int k = 0; k < 4; ++k) {
        HU ha, wa, wb;
        ha.u = hv[k]; wa.u = wA[j][k]; wb.u = wB[j][k];
        a0 = fdot2f(wa, ha, a0);
        a1 = fdot2f(wb, ha, a1);
      }
    }
#pragma unroll
    for (int off = 32; off; off >>= 1) {
      a0 += __shfl_xor(a0, off, 64);
      a1 += __shfl_xor(a1, off, 64);
    }
    const unsigned tg = (unsigned)t + 1u;
    unsigned int* slot = hpub + ((t & 1) << 11);
    if (lane == 0) {
      const float h0 = fast_tanh(a0);
      const float h1 = fast_tanh(a1);
      HU pk; pk.hf = __builtin_amdgcn_cvt_pkrtz(h0, h1);
      pub[wave] = pk.u;
      psm[wave] = dw0 * h0 + dw1 * h1;
    }
    BARK();  // bar1: pub + psm visible; all shh reads of step t done
    // issue next X row (normal cached load; position in queue is counted)
    {
      const int tn = (t + 1 < TT) ? t + 1 : t;
      const float* xp = X + tn * 64 + lane;
      asm volatile("global_load_dword %0, %1, off" : "=&v"(xq) : "v"(xp)
                   : "memory");
    }
    if (wave == 0) {
      if (t + 1 < TT) {
        // publish: ONE coalesced 16-packet burst (2 lines, single writer)
        if (tid < 16) {
          u2v pv; pv.x = pub[tid]; pv.y = tg;
          asm volatile("global_store_dwordx2 %0, %1, off sc0 sc1"
                       :: "v"(slot + 2 * (16 * b + tid)), "v"(pv) : "memory");
        }
        const unsigned int* b0 = slot + 2 * lane;
        const unsigned int* b1 = b0 + 1024;
        u2v A0, A1, A2, A3, A4, A5, A6, A7, A8, A9, Aa, Ab, Ac, Ad, Ae, Af;
        u2v B0, B1, B2, B3, B4, B5, B6, B7, B8, B9, Ba, Bb, Bc, Bd, Be, Bf;
        // WAW guard: retire previous step's stale batch (oldest 16);
        // leaves [xnext, store] = 2 in flight.
        asm volatile("s_waitcnt vmcnt(2)" ::: "memory");
        PISSUE(A, "");                              // queue: xnext,store,A
        PISSUE(B, "\n\ts_waitcnt vmcnt(16)");       // retires xnext+store+A
        REGBAR(A);
        bool useB = false;
        bool got = CHK(A);
        if (!got) {
          for (;;) {
            PISSUE(A, "\n\ts_waitcnt vmcnt(16)");   // reissue A; B retired
            REGBAR(B);
            if (CHK(B)) { useB = true; break; }
            PISSUE(B, "\n\ts_waitcnt vmcnt(16)");   // reissue B; A retired
            REGBAR(A);
            if (CHK(A)) { useB = false; break; }
          }
        }
        // every exit path leaves exactly one batch (16 loads) in flight
        if (useB) REPACK(B); else REPACK(A);
      }
    } else if (tid == 64) {
      // dense partial for step t (parallel with wave0's poll)
      float s = 0.f;
#pragma unroll
      for (int wv = 0; wv < 16; ++wv) s += psm[wv];
      yp[t * 64 + b] = s;
    }
    BARK();  // bar2: shh now holds h_t
  }
}

__global__ void esn_out(const float* __restrict__ X,
                        const float* __restrict__ wtil,
                        const float* __restrict__ yp,
                        const float* __restrict__ bptr,
                        float* __restrict__ out) {
  const int tid = threadIdx.x;
  const int lane = tid & 63;
  const int wave = tid >> 6;
  const int t = blockIdx.x * 4 + wave;
  float v = wtil[lane] * X[t * 64 + lane] + yp[t * 64 + lane];
#pragma unroll
  for (int off = 32; off; off >>= 1) v += __shfl_xor(v, off, 64);
  if (lane == 0) out[t] = v + bptr[0];
}

extern "C" void kernel_launch(void* const* d_in, const int* in_sizes, int n_in,
                              void* d_out, int out_size, void* d_ws, size_t ws_size,
                              hipStream_t stream) {
  const float* X   = (const float*)d_in[0];
  const float* C   = (const float*)d_in[1];
  const float* Win = (const float*)d_in[2];
  const float* W   = (const float*)d_in[3];
  const float* dW  = (const float*)d_in[4];
  const float* db  = (const float*)d_in[5];
  float* ws   = (float*)d_ws;
  float* M    = ws;
  float* wtil = ws + 131072;
  float* yp   = ws + 131200;
  unsigned int* hpub = (unsigned int*)(ws + 393344);

  esn_prep<<<2049, 64, 0, stream>>>(C, Win, dW, M, wtil);

  void* args[] = {(void*)&X, (void*)&M, (void*)&W, (void*)&dW,
                  (void*)&hpub, (void*)&yp};
  (void)hipLaunchCooperativeKernel(reinterpret_cast<void*>(&esn_recur), dim3(64),
                                   dim3(1024), args, 0, stream);

  esn_out<<<1024, 256, 0, stream>>>(X, wtil, yp, db, (float*)d_out);
}